// Round 12
// baseline (597.833 us; speedup 1.0000x reference)
//
#include <hip/hip_runtime.h>
#include <hip/hip_bf16.h>

#define NTOK  384
#define SPANS 73920          // 384*385/2
#define MTILES 584           // 73*8 so grid=584*8 maps cleanly onto 8 XCDs
#define MPAD  (MTILES * 128) // 74752
#define HD    1024
#define BK    32
#define KTS   (HD / BK)      // 32

typedef unsigned short u16;
typedef __attribute__((ext_vector_type(8))) short short8;
typedef __attribute__((ext_vector_type(4))) float floatx4;

// gfx9 s_waitcnt immediate: vmcnt[3:0]|[15:14], expcnt[6:4], lgkmcnt[11:8]
#define VM_IMM(N)      (((N) & 0xF) | (((N) >> 4) << 14) | (0x7 << 4) | (0xF << 8))
#define VM_LGKM0(N)    (((N) & 0xF) | (((N) >> 4) << 14) | (0x7 << 4) | (0x0 << 8))

__device__ __forceinline__ u16 f2bu(float x) {
  union { float f; unsigned u; } un; un.f = x;
  unsigned r = un.u + 0x7fffu + ((un.u >> 16) & 1u);   // RNE
  return (u16)(r >> 16);
}

__device__ __forceinline__ unsigned pk2(float a, float b) {
  union { __hip_bfloat162 h; unsigned u; } un;
  un.h = __float22bfloat162_rn(float2{a, b});
  return un.u;
}

__device__ __forceinline__ void gld_lds16(const void* g, void* l) {
  __builtin_amdgcn_global_load_lds(
      (const __attribute__((address_space(1))) void*)g,
      (__attribute__((address_space(3))) void*)l, 16, 0, 0);
}

// ---- prep: gather token embeddings as bf16 [384][1024] (A of the Y-GEMM) ----
__global__ void emb_gather(const int* __restrict__ sent, const int* __restrict__ pos,
                           const float* __restrict__ Wwrd, const float* __restrict__ Wpos,
                           u16* __restrict__ embB) {
  int t = blockIdx.x;           // token
  int c = threadIdx.x;          // 0..255
  int pt = pos[t], st = sent[t];
  #pragma unroll
  for (int u = 0; u < 4; ++u) {
    int col = u * 256 + c;
    float v = (col < 512) ? Wpos[(size_t)pt * 512 + col]
                          : Wwrd[(size_t)st * 512 + (col - 512)];
    embB[(size_t)t * HD + col] = f2bu(v);
  }
}

// ---- prep: span (i, end, 1/len) + scores init (folded) ----
__global__ void prep_spans(int* __restrict__ spI, int* __restrict__ spE, float* __restrict__ spInv,
                           float* __restrict__ scores, const float* __restrict__ bs2) {
  int rf = blockIdx.x * 256 + threadIdx.x;
  if (rf >= MPAD) return;
  int s = rf < SPANS ? rf : SPANS - 1;
  const int n = NTOK;
  double tn = 2.0 * n + 1.0;
  int i = (int)((tn - sqrt(tn * tn - 8.0 * (double)s)) * 0.5);
  if (i < 0) i = 0;
  if (i > n - 1) i = n - 1;
  #define OFF(ii) (((ii) * (2 * n - (ii) + 1)) / 2)
  while (i + 1 <= n - 1 && OFF(i + 1) <= s) ++i;
  while (i > 0 && OFF(i) > s) --i;
  int j = i + (s - OFF(i));
  #undef OFF
  spI[rf] = i;
  spE[rf] = j + 1;
  spInv[rf] = 1.0f / (float)(j + 1 - i);
  if (rf < SPANS) scores[rf] = bs2[0];
}

// ---- prep: transpose+cast the three 1024x1024 weight blocks to bf16 B^T [N][K] ----
__global__ void prep_castT(const float* __restrict__ Wd1, const float* __restrict__ Wd2,
                           const float* __restrict__ Ws1,
                           u16* __restrict__ o1, u16* __restrict__ o2, u16* __restrict__ o3) {
  int b = blockIdx.x;           // 3*1024 blocks
  int w = b >> 10, rem = b & 1023;
  int tk = rem >> 5, tn = rem & 31;
  const float* src = (w == 0) ? Wd1 : ((w == 1) ? Wd2 : Ws1);
  u16* dst = (w == 0) ? o1 : ((w == 1) ? o2 : o3);
  __shared__ u16 tile[32][33];
  int x = threadIdx.x & 31, y = threadIdx.x >> 5;   // y in 0..7
  int k0 = tk * 32, n0 = tn * 32;
  for (int yy = 0; yy < 32; yy += 8)
    tile[y + yy][x] = f2bu(src[(size_t)(k0 + y + yy) * HD + n0 + x]);
  __syncthreads();
  for (int yy = 0; yy < 32; yy += 8)
    dst[(size_t)(n0 + y + yy) * HD + k0 + x] = tile[x][y + yy];
}

// ---- prep: S0/S1/S2 = column sums of W_s1's feat rows (len/start/end, 16 each), exact fp32 ----
__global__ void prep_svec(const float* __restrict__ Ws1,
                          float* __restrict__ S0, float* __restrict__ S1v, float* __restrict__ S2v) {
  int c = blockIdx.x * 256 + threadIdx.x;
  if (c >= HD) return;
  float a = 0.f, b = 0.f, d = 0.f;
  for (int r = 0; r < 16; ++r) {
    a += Ws1[(size_t)(1024 + r) * HD + c];
    b += Ws1[(size_t)(1040 + r) * HD + c];
    d += Ws1[(size_t)(1056 + r) * HD + c];
  }
  S0[c] = a; S1v[c] = b; S2v[c] = d;
}

// ---- Qp'[t] = [0; cumsum(Y, rows)] + t*b1  (fp32, per-column scan).
// b1 folded: (Qp'[e]-Qp'[i])*inv = mean@W1 + b1 since (e-i)*inv = 1.
__global__ void yscan(const float* __restrict__ Y, float* __restrict__ Qp,
                      const float* __restrict__ b1) {
  __shared__ float buf[NTOK];
  int c = blockIdx.x;           // 0..1023
  int t = threadIdx.x;          // 0..383
  buf[t] = Y[(size_t)t * HD + c];
  __syncthreads();
  #pragma unroll
  for (int off = 1; off < NTOK; off <<= 1) {
    float add = (t >= off) ? buf[t - off] : 0.f;
    __syncthreads();
    buf[t] += add;
    __syncthreads();
  }
  float bc = b1[c];
  if (t == 0) Qp[c] = 0.f;
  Qp[(size_t)(t + 1) * HD + c] = buf[t] + (float)(t + 1) * bc;
}

// ---- GEMM: C[M,1024] = A[M,1024] @ B^T[1024,1024]^T (+ bias, relu)
// R7 structure: 128x128 tile, 4 waves of 64x64, 16x16x32 MFMA, BK=32,
// 0-conflict stripe layout (2 rows per 128-B stripe), two-barrier ping-pong.
// ASRC==0: A staged from global via global_load_lds (vmcnt(4) pipeline).
// ASRC==1: A-tile COMPUTED in-register from Qp' (h1 = relu((Qp'[e]-Qp'[i])*inv))
//          and ds_written into the same swizzled slots — bufA/expand deleted;
//          only B uses DMA (vmcnt(2) + lgkmcnt(0) before barrier).
// EPI==0: relu+bias, store bf16 C.  EPI==1: + feats affine, relu, dot W_s2,
// atomicAdd scores.  EPI==2: plain fp32 store, simple block mapping (Y-GEMM).
template <int EPI, int ASRC>
__global__ __launch_bounds__(256, 3) void gemm_bt(
    const u16* __restrict__ A, const u16* __restrict__ Bt,
    const float* __restrict__ bias, u16* __restrict__ C, float* __restrict__ Cf,
    const float* __restrict__ Qp,
    const int* __restrict__ spI, const int* __restrict__ spE, const float* __restrict__ spInv,
    const float* __restrict__ S0, const float* __restrict__ S1v, const float* __restrict__ S2v,
    const float* __restrict__ Ws2, float* __restrict__ scores) {
  __shared__ u16 As[2][128 * BK];   // 8 KB per buffer; [stripe(64)][128B]
  __shared__ u16 Bs[2][128 * BK];
  int bx = blockIdx.x;
  int mt, nt;
  if (EPI == 2) {
    nt = bx & 7; mt = bx >> 3;      // tiny GEMM: plain mapping
  } else {
    int xcd = bx & 7, k = bx >> 3;
    nt = k & 7;
    mt = xcd + 8 * (k >> 3);        // mt%8 == xcd; blocks per XCD share mt (A L2 reuse)
  }
  int m0 = mt * 128, n0 = nt * 128;
  int t = threadIdx.x, lane = t & 63, wid = t >> 6;
  int wm = wid >> 1, wn = wid & 1;
  int q = lane >> 4, r = lane & 15;

  floatx4 acc[4][4] = {};

  // ---- staging geometry (stripe s holds rows 2s,2s+1; sub=(row&1)*4+koct at
  // octet sub^(s&7); one op = 16 rows x 64B, swizzle invariant under +64 rows) ----
  int dsub = (lane & 7) ^ ((lane >> 3) & 7);
  int row0 = wid * 16 + 2 * (lane >> 3) + (dsub >> 2);
  int voff = row0 * HD + (dsub & 3) * 8;          // u16 elems; kt-invariant
  const u16* gA0 = A  + (size_t)m0 * HD;
  const u16* gB0 = Bt + (size_t)n0 * HD;
  int ldsOff0 = wid * 512;                        // u16; wave-uniform dests
  int ldsOff1 = 2048 + wid * 512;                 // +64 rows = +32 stripes

  // ASRC==1: hoisted Qp row pointers for the two rows this lane stages
  const float *pe0, *pi0, *pe1, *pi1;
  float inv0, inv1;
  if (ASRC == 1) {
    int g0 = m0 + row0, g1 = g0 + 64;
    int cofs = (dsub & 3) * 8;
    pe0 = Qp + (size_t)spE[g0] * HD + cofs;  pi0 = Qp + (size_t)spI[g0] * HD + cofs;
    pe1 = Qp + (size_t)spE[g1] * HD + cofs;  pi1 = Qp + (size_t)spI[g1] * HD + cofs;
    inv0 = spInv[g0]; inv1 = spInv[g1];
  }

  auto stage = [&](int kt, int b) {
    const u16* pb = gB0 + voff + kt * BK;
    gld_lds16(pb,                   &Bs[b][ldsOff0]);
    gld_lds16(pb + (size_t)64 * HD, &Bs[b][ldsOff1]);
    if (ASRC == 0) {
      const u16* pa = gA0 + voff + kt * BK;
      gld_lds16(pa,                   &As[b][ldsOff0]);
      gld_lds16(pa + (size_t)64 * HD, &As[b][ldsOff1]);
    } else {
      int cb = kt * BK;
      float4 x0 = *(const float4*)(pe0 + cb), x1 = *(const float4*)(pe0 + cb + 4);
      float4 y0 = *(const float4*)(pi0 + cb), y1 = *(const float4*)(pi0 + cb + 4);
      float4 u0 = *(const float4*)(pe1 + cb), u1 = *(const float4*)(pe1 + cb + 4);
      float4 v0 = *(const float4*)(pi1 + cb), v1 = *(const float4*)(pi1 + cb + 4);
      float a0 = fmaxf((x0.x - y0.x) * inv0, 0.f), a1 = fmaxf((x0.y - y0.y) * inv0, 0.f);
      float a2 = fmaxf((x0.z - y0.z) * inv0, 0.f), a3 = fmaxf((x0.w - y0.w) * inv0, 0.f);
      float a4 = fmaxf((x1.x - y1.x) * inv0, 0.f), a5 = fmaxf((x1.y - y1.y) * inv0, 0.f);
      float a6 = fmaxf((x1.z - y1.z) * inv0, 0.f), a7 = fmaxf((x1.w - y1.w) * inv0, 0.f);
      uint4 w0 = {pk2(a0, a1), pk2(a2, a3), pk2(a4, a5), pk2(a6, a7)};
      *(uint4*)(&As[b][ldsOff0 + lane * 8]) = w0;
      float b0 = fmaxf((u0.x - v0.x) * inv1, 0.f), b1v = fmaxf((u0.y - v0.y) * inv1, 0.f);
      float b2 = fmaxf((u0.z - v0.z) * inv1, 0.f), b3 = fmaxf((u0.w - v0.w) * inv1, 0.f);
      float b4 = fmaxf((u1.x - v1.x) * inv1, 0.f), b5 = fmaxf((u1.y - v1.y) * inv1, 0.f);
      float b6 = fmaxf((u1.z - v1.z) * inv1, 0.f), b7 = fmaxf((u1.w - v1.w) * inv1, 0.f);
      uint4 w1 = {pk2(b0, b1v), pk2(b2, b3), pk2(b4, b5), pk2(b6, b7)};
      *(uint4*)(&As[b][ldsOff1 + lane * 8]) = w1;
    }
  };

  // ---- fragment read offsets (u16 elements) ----
  int oct = (((r & 1) << 2) + q) ^ ((r >> 1) & 7);
  int aoff[4], boff[4];
  #pragma unroll
  for (int x = 0; x < 4; ++x) {
    aoff[x] = (wm * 32 + x * 8 + (r >> 1)) * 64 + oct * 8;
    boff[x] = (wn * 32 + x * 8 + (r >> 1)) * 64 + oct * 8;
  }

  auto compute = [&](int b) {
    short8 af[4];
    #pragma unroll
    for (int x = 0; x < 4; ++x) af[x] = *(const short8*)(&As[b][aoff[x]]);
    #pragma unroll
    for (int ni = 0; ni < 4; ++ni) {
      short8 bf = *(const short8*)(&Bs[b][boff[ni]]);
      #pragma unroll
      for (int mi = 0; mi < 4; ++mi)
        acc[mi][ni] = __builtin_amdgcn_mfma_f32_16x16x32_bf16(af[mi], bf, acc[mi][ni], 0, 0, 0);
    }
  };

  const int NSTG = (ASRC == 0) ? 4 : 2;   // DMA ops per stage
  stage(0, 0);
  #pragma unroll 1
  for (int kt = 0; kt < KTS; ++kt) {
    int cur = kt & 1;
    if (kt < KTS - 1) {
      stage(kt + 1, cur ^ 1);
      if (ASRC == 0) __builtin_amdgcn_s_waitcnt(VM_IMM(4));
      else           __builtin_amdgcn_s_waitcnt(VM_LGKM0(2));  // B(kt) done, own ds_writes done
    } else {
      if (ASRC == 0) __builtin_amdgcn_s_waitcnt(VM_IMM(0));
      else           __builtin_amdgcn_s_waitcnt(VM_LGKM0(0));
    }
    __builtin_amdgcn_s_barrier();
    compute(cur);
    __builtin_amdgcn_s_barrier();                 // all waves done reading buf cur
  }
  (void)NSTG;

  if (EPI == 2) {
    #pragma unroll
    for (int mi = 0; mi < 4; ++mi) {
      int rowb = m0 + wm * 64 + mi * 16 + q * 4;
      #pragma unroll
      for (int ni = 0; ni < 4; ++ni) {
        int col = n0 + wn * 64 + ni * 16 + r;
        #pragma unroll
        for (int e = 0; e < 4; ++e)
          Cf[(size_t)(rowb + e) * HD + col] = acc[mi][ni][e];
      }
    }
  } else if (EPI == 0) {
    #pragma unroll
    for (int mi = 0; mi < 4; ++mi) {
      int rowb = m0 + wm * 64 + mi * 16 + q * 4;
      #pragma unroll
      for (int ni = 0; ni < 4; ++ni) {
        int col = n0 + wn * 64 + ni * 16 + r;
        float bcol = bias[col];
        #pragma unroll
        for (int e = 0; e < 4; ++e) {
          float v = acc[mi][ni][e] + bcol;
          v = v > 0.f ? v : 0.f;
          C[(size_t)(rowb + e) * HD + col] = f2bu(v);
        }
      }
    }
  } else {
    float bcol[4], s0c[4], s1c[4], s2c[4], wsc[4];
    #pragma unroll
    for (int ni = 0; ni < 4; ++ni) {
      int col = n0 + wn * 64 + ni * 16 + r;
      bcol[ni] = bias[col]; s0c[ni] = S0[col]; s1c[ni] = S1v[col];
      s2c[ni] = S2v[col];  wsc[ni] = Ws2[col];
    }
    #pragma unroll
    for (int mi = 0; mi < 4; ++mi) {
      int rowb = m0 + wm * 64 + mi * 16 + q * 4;
      #pragma unroll
      for (int e = 0; e < 4; ++e) {
        int row = rowb + e;
        float fi = (float)spI[row];
        float fe = (float)spE[row];
        float fl = fe - fi;
        float p = 0.f;
        #pragma unroll
        for (int ni = 0; ni < 4; ++ni) {
          float v = acc[mi][ni][e] + bcol[ni] + fl * s0c[ni] + fi * s1c[ni] + fe * s2c[ni];
          v = v > 0.f ? v : 0.f;
          p += v * wsc[ni];
        }
        p += __shfl_xor(p, 1);
        p += __shfl_xor(p, 2);
        p += __shfl_xor(p, 4);
        p += __shfl_xor(p, 8);
        if (r == 0 && row < SPANS) atomicAdd(&scores[row], p);
      }
    }
  }
}

extern "C" void kernel_launch(void* const* d_in, const int* in_sizes, int n_in,
                              void* d_out, int out_size, void* d_ws, size_t ws_size,
                              hipStream_t stream) {
  const int*   sent = (const int*)d_in[0];
  const int*   pos  = (const int*)d_in[1];
  const float* Wwrd = (const float*)d_in[2];
  const float* Wpos = (const float*)d_in[3];
  const float* Wd1  = (const float*)d_in[4];
  const float* bd1  = (const float*)d_in[5];
  const float* Wd2  = (const float*)d_in[6];
  const float* bd2  = (const float*)d_in[7];
  const float* Ws1  = (const float*)d_in[8];
  const float* bs1  = (const float*)d_in[9];
  const float* Ws2  = (const float*)d_in[10];
  const float* bs2  = (const float*)d_in[11];
  float* scores = (float*)d_out;

  char* w = (char*)d_ws;
  size_t o = 0;
  auto alloc = [&](size_t bytes) {
    char* p = w + o;
    o = (o + bytes + 255) & ~(size_t)255;
    return p;
  };
  int*   spI   = (int*)  alloc((size_t)MPAD * 4);
  int*   spE   = (int*)  alloc((size_t)MPAD * 4);
  float* spInv = (float*)alloc((size_t)MPAD * 4);
  float* S0    = (float*)alloc(4096);
  float* S1v   = (float*)alloc(4096);
  float* S2v   = (float*)alloc(4096);
  u16*   embB  = (u16*)  alloc((size_t)NTOK * HD * 2);
  float* Ybuf  = (float*)alloc((size_t)NTOK * HD * 4);
  float* Qp    = (float*)alloc((size_t)(NTOK + 1) * HD * 4);
  u16* Wd1t = (u16*)alloc((size_t)HD * HD * 2);
  u16* Wd2t = (u16*)alloc((size_t)HD * HD * 2);
  u16* Ws1t = (u16*)alloc((size_t)HD * HD * 2);
  u16* bufB = (u16*)alloc((size_t)MPAD * HD * 2);

  emb_gather<<<NTOK, 256, 0, stream>>>(sent, pos, Wwrd, Wpos, embB);
  prep_spans<<<(MPAD + 255) / 256, 256, 0, stream>>>(spI, spE, spInv, scores, bs2);
  prep_castT<<<3 * 1024, 256, 0, stream>>>(Wd1, Wd2, Ws1, Wd1t, Wd2t, Ws1t);
  prep_svec <<<4, 256, 0, stream>>>(Ws1, S0, S1v, S2v);

  // Y = emb @ Wd1  (384x1024x1024, 24 blocks, fp32 out)
  gemm_bt<2, 0><<<(NTOK / 128) * 8, 256, 0, stream>>>(embB, Wd1t, nullptr, nullptr, Ybuf,
                                                      nullptr, nullptr, nullptr, nullptr,
                                                      nullptr, nullptr, nullptr, nullptr, nullptr);
  yscan<<<HD, NTOK, 0, stream>>>(Ybuf, Qp, bd1);

  // h2 = relu(h1 @ Wd2 + b2), h1 computed on the fly from Qp'
  gemm_bt<0, 1><<<MTILES * 8, 256, 0, stream>>>(nullptr, Wd2t, bd2, bufB, nullptr,
                                                Qp, spI, spE, spInv,
                                                nullptr, nullptr, nullptr, nullptr, nullptr);
  // scores
  gemm_bt<1, 0><<<MTILES * 8, 256, 0, stream>>>(bufB, Ws1t, bs1, nullptr, nullptr,
                                                nullptr, spI, spE, spInv,
                                                S0, S1v, S2v, Ws2, scores);
}